// Round 3
// baseline (609.213 us; speedup 1.0000x reference)
//
#include <hip/hip_runtime.h>
#include <hip/hip_bf16.h>

// CausalLinearAttention — bf16-MFMA, FUSED single-kernel segment scan.
// N=4, L=8192, H=16, E=D=64.
// Decoupled look-back (mask-based, no chain): each block computes its
// segment's local state (phase P), publishes it (agent-scope release),
// waits for all predecessors' masks (acquire), sums partials, then runs
// the main per-chunk loop. Grid = NHh*G = 1024 = exact residency
// (38.1 KB LDS -> 4 blocks/CU, VGPR capped by __launch_bounds__(256,4)),
// so all blocks co-resident -> no deadlock regardless of dispatch order.

#define Nn   4
#define Ll   8192
#define Hh   16
#define NHh  64
#define CCH  64          // chunk size (positions)
#define LDB  72          // bf16 LDS row stride: 144 B, 16B-multiple
#define SLOT 4160        // per-(nh,seg) ws slot: 4096 state + 64 ksum floats
#define EPSF 1e-6f

typedef __attribute__((ext_vector_type(8))) short short8;   // 8 bf16 = 4 VGPRs
typedef __attribute__((ext_vector_type(4))) float floatx4;  // MFMA accumulator

__device__ __forceinline__ float elu1(float x) {
  return x > 0.f ? x + 1.f : __expf(x);
}

__device__ __forceinline__ float4 elu4(float4 v) {
  v.x = elu1(v.x); v.y = elu1(v.y); v.z = elu1(v.z); v.w = elu1(v.w);
  return v;
}

__device__ __forceinline__ floatx4 mfma16(short8 a, short8 b, floatx4 c) {
  return __builtin_amdgcn_mfma_f32_16x16x32_bf16(a, b, c, 0, 0, 0);
}

// lgkm-only barrier: my ds ops complete, then block-sync. vmcnt NOT drained,
// so prefetched global loads / pending global stores stay in flight.
// 0xc07f = vmcnt(63) expcnt(7) lgkmcnt(0).
__device__ __forceinline__ void bar_lgkm() {
  __builtin_amdgcn_s_waitcnt(0xc07f);
  __builtin_amdgcn_s_barrier();
  __builtin_amdgcn_sched_barrier(0);  // no code motion across the barrier
}

// load an A/B fragment: row-major [row][k], 8 consecutive bf16 at
// k = kh*32 + quad*8
__device__ __forceinline__ short8 frag_ld(const __hip_bfloat16* base, int row,
                                          int kh, int quad) {
  return *(const short8*)(base + row * LDB + kh * 32 + quad * 8);
}

// pack 4 floats -> 4 bf16, single 8-byte LDS write (dst must be 8B-aligned)
__device__ __forceinline__ void st4bf(__hip_bfloat16* dst, float a, float b,
                                      float c, float d) {
  union { __hip_bfloat16 h[4]; uint2 u; } pk;
  pk.h[0] = __float2bfloat16(a); pk.h[1] = __float2bfloat16(b);
  pk.h[2] = __float2bfloat16(c); pk.h[3] = __float2bfloat16(d);
  *(uint2*)dst = pk.u;
}

__device__ __forceinline__ float bf2f(short s) {
  union { unsigned u; float f; } cv;
  cv.u = ((unsigned)(unsigned short)s) << 16;
  return cv.f;
}

__device__ __forceinline__ float sum8bf(short8 v) {
  float s = 0.f;
#pragma unroll
  for (int i = 0; i < 8; ++i) s += bf2f(v[i]);
  return s;
}

__device__ __forceinline__ float ld_agent_f32(const float* p) {
  union { unsigned u; float f; } cv;
  cv.u = __hip_atomic_load((const unsigned*)p, __ATOMIC_RELAXED,
                           __HIP_MEMORY_SCOPE_AGENT);
  return cv.f;
}

// ---------------------------------------------------------------- zero
__global__ void la_zero(unsigned* __restrict__ masks) {
  masks[threadIdx.x] = 0u;
}

// ---------------------------------------------------------------- fused
__global__ __launch_bounds__(256, 4) void la_fused(
    const float* __restrict__ Qg, const float* __restrict__ Kg,
    const float* __restrict__ Vg, float* __restrict__ ws,
    float* __restrict__ out, int G, int Lseg) {
  const int bid = blockIdx.x;
  const int nh = bid / G, g = bid % G;
  const int n = nh / Hh, h = nh % Hh;
  const int t = threadIdx.x;
  const int wave = t >> 6, lane = t & 63, m = lane & 15, quad = lane >> 4;
  const int row = t >> 2, q4 = t & 3;      // row-major staging coords
  const int jr0 = m * 4;                   // 4x4-block transposed staging
  const int er0 = wave * 16 + quad * 4;

  __shared__ __hip_bfloat16 QPb[64 * LDB];  // Q [i][e] -> masked P [i][j]
  __shared__ __hip_bfloat16 Kb [64 * LDB];  // K [j][e] -> S^T snapshot [d][e]
  __shared__ __hip_bfloat16 Ktb[64 * LDB];  // K^T [e][j]
  __shared__ __hip_bfloat16 Vtb[64 * LDB];  // V^T [d][j]
  __shared__ float ksum[64];
  __shared__ float kpart[4][64];

  unsigned* maskp =
      (unsigned*)(ws + (size_t)NHh * G * SLOT) + nh;  // per-nh bitmask

  floatx4 Sacc[4];  // S^T tiles: rows d = 16*wave+quad*4+r, cols e = 16*b+m
  const floatx4 z4 = {0.f, 0.f, 0.f, 0.f};
#pragma unroll
  for (int b = 0; b < 4; ++b) Sacc[b] = z4;

  const int nchunk = Lseg / CCH;  // >= 8 when G<=16; even

  // ============================ phase P: local partial state (pass1 body)
  if (G > 1 && g < G - 1) {
    // double buffers alias the main-loop arrays: buf0=(Ktb,Vtb), buf1=(QPb,Kb)
    __hip_bfloat16* kt0 = Ktb; __hip_bfloat16* vt0 = Vtb;
    __hip_bfloat16* kt1 = QPb; __hip_bfloat16* vt1 = Kb;
    float kpriv[4] = {0.f, 0.f, 0.f, 0.f};

#define P_LOAD(KR, VR, c_) do { \
    const size_t gb_ = \
        ((size_t)((n * Ll + g * Lseg + (c_) * CCH + jr0) * Hh + h)) * 64 + er0; \
    KR[0] = *(const float4*)(Kg + gb_);        \
    KR[1] = *(const float4*)(Kg + gb_ + 1024); \
    KR[2] = *(const float4*)(Kg + gb_ + 2048); \
    KR[3] = *(const float4*)(Kg + gb_ + 3072); \
    VR[0] = *(const float4*)(Vg + gb_);        \
    VR[1] = *(const float4*)(Vg + gb_ + 1024); \
    VR[2] = *(const float4*)(Vg + gb_ + 2048); \
    VR[3] = *(const float4*)(Vg + gb_ + 3072); \
  } while (0)

#define P_STAGE(KR, VR, kt_, vt_) do { \
    float4 e0 = elu4(KR[0]), e1 = elu4(KR[1]), e2 = elu4(KR[2]), e3 = elu4(KR[3]); \
    kpriv[0] += e0.x + e1.x + e2.x + e3.x; \
    kpriv[1] += e0.y + e1.y + e2.y + e3.y; \
    kpriv[2] += e0.z + e1.z + e2.z + e3.z; \
    kpriv[3] += e0.w + e1.w + e2.w + e3.w; \
    st4bf(&(kt_)[(er0 + 0) * LDB + jr0], e0.x, e1.x, e2.x, e3.x); \
    st4bf(&(kt_)[(er0 + 1) * LDB + jr0], e0.y, e1.y, e2.y, e3.y); \
    st4bf(&(kt_)[(er0 + 2) * LDB + jr0], e0.z, e1.z, e2.z, e3.z); \
    st4bf(&(kt_)[(er0 + 3) * LDB + jr0], e0.w, e1.w, e2.w, e3.w); \
    st4bf(&(vt_)[(er0 + 0) * LDB + jr0], VR[0].x, VR[1].x, VR[2].x, VR[3].x); \
    st4bf(&(vt_)[(er0 + 1) * LDB + jr0], VR[0].y, VR[1].y, VR[2].y, VR[3].y); \
    st4bf(&(vt_)[(er0 + 2) * LDB + jr0], VR[0].z, VR[1].z, VR[2].z, VR[3].z); \
    st4bf(&(vt_)[(er0 + 3) * LDB + jr0], VR[0].w, VR[1].w, VR[2].w, VR[3].w); \
  } while (0)

#define P_MFMA(kt_, vt_) do { \
    const short8 a0 = frag_ld((vt_), 16 * wave + m, 0, quad); \
    const short8 a1 = frag_ld((vt_), 16 * wave + m, 1, quad); \
    __builtin_amdgcn_s_setprio(1); \
    _Pragma("unroll") \
    for (int b = 0; b < 4; ++b) { \
      Sacc[b] = mfma16(a0, frag_ld((kt_), 16 * b + m, 0, quad), Sacc[b]); \
      Sacc[b] = mfma16(a1, frag_ld((kt_), 16 * b + m, 1, quad), Sacc[b]); \
    } \
    __builtin_amdgcn_s_setprio(0); \
  } while (0)

    float4 ka[4], va[4], kb2[4], vb2[4];
    P_LOAD(ka, va, 0);
    P_LOAD(kb2, vb2, 1);
    P_STAGE(ka, va, kt0, vt0);
    for (int c = 0; c < nchunk; c += 2) {
      if (c + 2 < nchunk) P_LOAD(ka, va, c + 2);
      bar_lgkm();                                   // buf0 (chunk c) visible
      P_MFMA(kt0, vt0);
      P_STAGE(kb2, vb2, kt1, vt1);
      if (c + 3 < nchunk) P_LOAD(kb2, vb2, c + 3);
      bar_lgkm();                                   // buf1 (chunk c+1) visible
      P_MFMA(kt1, vt1);
      if (c + 2 < nchunk) P_STAGE(ka, va, kt0, vt0);
    }
#undef P_LOAD
#undef P_STAGE
#undef P_MFMA

    // reduce ksum partials over the 16 m-lanes (same (wave,quad) -> same e's)
#pragma unroll
    for (int i = 0; i < 4; ++i) {
      kpriv[i] += __shfl_xor(kpriv[i], 1);
      kpriv[i] += __shfl_xor(kpriv[i], 2);
      kpriv[i] += __shfl_xor(kpriv[i], 4);
      kpriv[i] += __shfl_xor(kpriv[i], 8);
    }
    // publish local state
    float* slotw = ws + (size_t)(nh * G + g) * SLOT;
#pragma unroll
    for (int b = 0; b < 4; ++b)
#pragma unroll
      for (int r = 0; r < 4; ++r) {
        const int d = 16 * wave + quad * 4 + r, e = 16 * b + m;
        slotw[d * 64 + e] = Sacc[b][r];
      }
    if (m == 0)
#pragma unroll
      for (int i = 0; i < 4; ++i) slotw[4096 + er0 + i] = kpriv[i];
    __syncthreads();  // drains vmcnt: all publish stores complete (in L2)
    if (t == 0)
      __hip_atomic_fetch_or(maskp, 1u << g, __ATOMIC_RELEASE,
                            __HIP_MEMORY_SCOPE_AGENT);  // wbL2 + IF-visible
    // reset accumulator for the main loop (prefix goes here)
#pragma unroll
    for (int b = 0; b < 4; ++b) Sacc[b] = z4;
  }

  // ============================ look-back: wait + sum predecessors
  float ks_init = 0.f;
  if (G > 1 && g > 0) {
    const unsigned need = (1u << g) - 1u;
    if (t == 0) {
      int iter = 0;
      while ((__hip_atomic_load(maskp, __ATOMIC_ACQUIRE,
                                __HIP_MEMORY_SCOPE_AGENT) & need) != need &&
             iter < (1 << 24)) {
        __builtin_amdgcn_s_sleep(2);
        ++iter;
      }
    }
    __syncthreads();
    // per-thread acquire: orders + invalidates stale L1/L2 lines (cross-XCD)
    (void)__hip_atomic_load(maskp, __ATOMIC_ACQUIRE, __HIP_MEMORY_SCOPE_AGENT);
    for (int gp = 0; gp < g; ++gp) {
      const float* base = ws + (size_t)(nh * G + gp) * SLOT;
#pragma unroll
      for (int b = 0; b < 4; ++b)
#pragma unroll
        for (int r = 0; r < 4; ++r) {
          const int d = 16 * wave + quad * 4 + r, e = 16 * b + m;
          Sacc[b][r] += ld_agent_f32(base + d * 64 + e);
        }
      if (t < 64) ks_init += ld_agent_f32(base + 4096 + t);
    }
  }
  if (t < 64) ksum[t] = ks_init;
  __syncthreads();  // LDS free of phase-P use; ksum visible

  // ============================ main loop (pass3 body)
  for (int c = 0; c < nchunk; ++c) {
    const int lbase = g * Lseg + c * CCH;
    // ---- phase A: issue Q,K,V loads; stage Q,K (V deferred to phase C)
    const size_t gbr = ((size_t)((n * Ll + lbase + row) * Hh + h)) * 64;
    const size_t gbv = ((size_t)((n * Ll + lbase + jr0) * Hh + h)) * 64 + er0;
    float4 qr[4], kr[4];
#pragma unroll
    for (int u = 0; u < 4; ++u) {
      const int col = u * 16 + q4 * 4;
      qr[u] = *(const float4*)(Qg + gbr + col);
      kr[u] = *(const float4*)(Kg + gbr + col);
    }
    float4 vr0 = *(const float4*)(Vg + gbv);
    float4 vr1 = *(const float4*)(Vg + gbv + 1024);
    float4 vr2 = *(const float4*)(Vg + gbv + 2048);
    float4 vr3 = *(const float4*)(Vg + gbv + 3072);
#pragma unroll
    for (int u = 0; u < 4; ++u) {
      const int col = u * 16 + q4 * 4;
      float4 qv = elu4(qr[u]);
      float4 kv = elu4(kr[u]);
      st4bf(&QPb[row * LDB + col], qv.x, qv.y, qv.z, qv.w);
      st4bf(&Kb [row * LDB + col], kv.x, kv.y, kv.z, kv.w);
      Ktb[(col + 0) * LDB + row] = __float2bfloat16(kv.x);
      Ktb[(col + 1) * LDB + row] = __float2bfloat16(kv.y);
      Ktb[(col + 2) * LDB + row] = __float2bfloat16(kv.z);
      Ktb[(col + 3) * LDB + row] = __float2bfloat16(kv.w);
    }
    bar_lgkm();  // B1: Q,K tiles staged (V loads still in flight)

    // ---- phase B: m1 (sc = Q K^T) + denominator in registers
    const short8 qa0 = frag_ld(QPb, 16 * wave + m, 0, quad);
    const short8 qa1 = frag_ld(QPb, 16 * wave + m, 1, quad);
    floatx4 sc[4];
    __builtin_amdgcn_s_setprio(1);
#pragma unroll
    for (int b = 0; b < 4; ++b) {
      sc[b] = mfma16(qa0, frag_ld(Kb, 16 * b + m, 0, quad), z4);
      sc[b] = mfma16(qa1, frag_ld(Kb, 16 * b + m, 1, quad), sc[b]);
    }
    __builtin_amdgcn_s_setprio(0);
    // dden for row i' = 16*wave + m from register fragments:
    // qa0 covers e = quad*8..+7, qa1 covers e = 32+quad*8..+7
    float dpart = 0.f;
    {
      const float* ks0 = &ksum[quad * 8];        // broadcast reads
      const float* ks1 = &ksum[32 + quad * 8];
#pragma unroll
      for (int u = 0; u < 8; ++u) dpart += bf2f(qa0[u]) * ks0[u];
#pragma unroll
      for (int u = 0; u < 8; ++u) dpart += bf2f(qa1[u]) * ks1[u];
    }
    dpart += __shfl_xor(dpart, 16);
    dpart += __shfl_xor(dpart, 32);  // all lanes: full dden[16*wave + m]
    // rs[r] = sum_j masked sc; z[r] in registers
    float z[4];
#pragma unroll
    for (int r = 0; r < 4; ++r) {
      const int i = 16 * wave + quad * 4 + r;
      float rs = 0.f;
#pragma unroll
      for (int b = 0; b < 4; ++b) {
        const int j = 16 * b + m;
        rs += (j <= i) ? sc[b][r] : 0.f;
      }
      rs += __shfl_xor(rs, 1);
      rs += __shfl_xor(rs, 2);
      rs += __shfl_xor(rs, 4);
      rs += __shfl_xor(rs, 8);
      const float den = __shfl(dpart, quad * 4 + r);  // lane m' = quad*4+r
      z[r] = 1.f / (den + rs + EPSF);
    }
    bar_lgkm();  // B2: Q/Kb reads done; QPb->P, Kb->snapshot next

    // ---- phase C: masked P -> QPb; S^T snapshot -> Kb; stage V -> Vtb
#pragma unroll
    for (int b = 0; b < 4; ++b)
#pragma unroll
      for (int r = 0; r < 4; ++r) {
        const int i = 16 * wave + quad * 4 + r, j = 16 * b + m;
        QPb[i * LDB + j] = __float2bfloat16(j <= i ? sc[b][r] : 0.f);
        Kb[i * LDB + j] = __float2bfloat16(Sacc[b][r]);  // rows d, cols e
      }
    st4bf(&Vtb[(er0 + 0) * LDB + jr0], vr0.x, vr1.x, vr2.x, vr3.x);
    st4bf(&Vtb[(er0 + 1) * LDB + jr0], vr0.y, vr1.y, vr2.y, vr3.y);
    st4bf(&Vtb[(er0 + 2) * LDB + jr0], vr0.z, vr1.z, vr2.z, vr3.z);
    st4bf(&Vtb[(er0 + 3) * LDB + jr0], vr0.w, vr1.w, vr2.w, vr3.w);
    bar_lgkm();  // B3: P + snapshot + V visible

    // ---- phase D: m2 (Q S_prev) + m3 (P V) + m4 (S += V^T K)
    const short8 pa0 = frag_ld(QPb, 16 * wave + m, 0, quad);
    const short8 pa1 = frag_ld(QPb, 16 * wave + m, 1, quad);
    const short8 va0 = frag_ld(Vtb, 16 * wave + m, 0, quad);
    const short8 va1 = frag_ld(Vtb, 16 * wave + m, 1, quad);
    floatx4 O[4];
    __builtin_amdgcn_s_setprio(1);
#pragma unroll
    for (int b = 0; b < 4; ++b) {
      O[b] = mfma16(qa0, frag_ld(Kb, 16 * b + m, 0, quad), z4);
      O[b] = mfma16(qa1, frag_ld(Kb, 16 * b + m, 1, quad), O[b]);
      O[b] = mfma16(pa0, frag_ld(Vtb, 16 * b + m, 0, quad), O[b]);
      O[b] = mfma16(pa1, frag_ld(Vtb, 16 * b + m, 1, quad), O[b]);
      Sacc[b] = mfma16(va0, frag_ld(Ktb, 16 * b + m, 0, quad), Sacc[b]);
      Sacc[b] = mfma16(va1, frag_ld(Ktb, 16 * b + m, 1, quad), Sacc[b]);
    }
    __builtin_amdgcn_s_setprio(0);
    {  // ksum partials for next chunk
      const short8 x0 = *(const short8*)(&Ktb[lane * LDB + wave * 16]);
      const short8 x1 = *(const short8*)(&Ktb[lane * LDB + wave * 16 + 8]);
      kpart[wave][lane] = sum8bf(x0) + sum8bf(x1);
    }
    const size_t ob = ((size_t)((n * Ll + lbase) * Hh + h)) * 64;
#pragma unroll
    for (int r = 0; r < 4; ++r) {
      const int i = 16 * wave + quad * 4 + r;
#pragma unroll
      for (int b = 0; b < 4; ++b)
        out[ob + (size_t)i * (Hh * 64) + 16 * b + m] = O[b][r] * z[r];
    }
    bar_lgkm();  // B4: all LDS reads of this chunk done (stores NOT drained)
    if (t < 64)
      ksum[t] += kpart[0][t] + kpart[1][t] + kpart[2][t] + kpart[3][t];
  }
}

// ---------------------------------------------------------------- launch
extern "C" void kernel_launch(void* const* d_in, const int* in_sizes, int n_in,
                              void* d_out, int out_size, void* d_ws, size_t ws_size,
                              hipStream_t stream) {
  (void)in_sizes; (void)n_in; (void)out_size;
  const float* Qg = (const float*)d_in[0];
  const float* Kg = (const float*)d_in[1];
  const float* Vg = (const float*)d_in[2];
  float* out = (float*)d_out;
  float* ws = (float*)d_ws;

  const size_t per_seg = (size_t)NHh * SLOT * sizeof(float);
  int G = 1;
  if (ws_size >= 16 * per_seg + 1024) G = 16;
  else if (ws_size >= 8 * per_seg + 1024) G = 8;
  else if (ws_size >= 4 * per_seg + 1024) G = 4;
  else if (ws_size >= 2 * per_seg + 1024) G = 2;
  const int Lseg = Ll / G;

  if (G > 1) {
    unsigned* masks = (unsigned*)(ws + (size_t)NHh * G * SLOT);
    la_zero<<<1, NHh, 0, stream>>>(masks);
  }
  la_fused<<<NHh * G, 256, 0, stream>>>(Qg, Kg, Vg, ws, out, G, Lseg);
}

// Round 5
// 475.079 us; speedup vs baseline: 1.2823x; 1.2823x over previous
//
#include <hip/hip_runtime.h>
#include <hip/hip_bf16.h>

// CausalLinearAttention — bf16-MFMA, 3-pass segment-parallel scan.
// N=4, L=8192, H=16, E=D=64. This revision (vs round-2, reverting round-3
// fusion which regressed):
//  * pass1 rewritten BARRIER-FREE: each wave independently scans a
//    contiguous quarter of the segment in 32-position chunks with
//    wave-private LDS tiles ([64][36] bf16, b64 frag reads) and a full
//    64x64 S^T in 16 accumulators. No __syncthreads in the loop -> 16
//    independent wave streams/CU, no lockstep burst-drain.
//    Cross-wave reduction at the end (4 rounds, LDS overlay).
//  * pass2 / pass3 unchanged from round-2 (known 117 us).
// (Resubmission of round-4 source: bench infra failed, no measurement.)

#define Nn   4
#define Ll   8192
#define Hh   16
#define NHh  64
#define CCH  64          // pass3 chunk size (positions)
#define LDB  72          // pass3 bf16 LDS row stride
#define SLOT 4160        // per-(nh,seg) ws slot: 4096 state + 64 ksum floats
#define EPSF 1e-6f

typedef __attribute__((ext_vector_type(8))) short short8;   // 8 bf16 = 4 VGPRs
typedef __attribute__((ext_vector_type(4))) float floatx4;  // MFMA accumulator

__device__ __forceinline__ float elu1(float x) {
  return x > 0.f ? x + 1.f : __expf(x);
}

__device__ __forceinline__ float4 elu4(float4 v) {
  v.x = elu1(v.x); v.y = elu1(v.y); v.z = elu1(v.z); v.w = elu1(v.w);
  return v;
}

__device__ __forceinline__ floatx4 mfma16(short8 a, short8 b, floatx4 c) {
  return __builtin_amdgcn_mfma_f32_16x16x32_bf16(a, b, c, 0, 0, 0);
}

// lgkm-only barrier: my ds ops complete, then block-sync. vmcnt NOT drained.
// 0xc07f = vmcnt(63) expcnt(7) lgkmcnt(0).
__device__ __forceinline__ void bar_lgkm() {
  __builtin_amdgcn_s_waitcnt(0xc07f);
  __builtin_amdgcn_s_barrier();
  __builtin_amdgcn_sched_barrier(0);
}

// pass3 fragment load: row-major [row][k], 8 bf16 at k = kh*32 + quad*8
__device__ __forceinline__ short8 frag_ld(const __hip_bfloat16* base, int row,
                                          int kh, int quad) {
  return *(const short8*)(base + row * LDB + kh * 32 + quad * 8);
}

// pass1 fragment load from [64][36] tile: 8 bf16 at k = quad*8 (two 8B reads)
__device__ __forceinline__ short8 frag36(const short* base, int row, int quad) {
  union { short8 v; uint2 p[2]; } u;
  const short* p = base + row * 36 + quad * 8;
  u.p[0] = *(const uint2*)(p);
  u.p[1] = *(const uint2*)(p + 4);
  return u.v;
}

// pack 4 floats -> 4 bf16, single 8-byte LDS write (dst must be 8B-aligned)
__device__ __forceinline__ void st4bf(__hip_bfloat16* dst, float a, float b,
                                      float c, float d) {
  union { __hip_bfloat16 h[4]; uint2 u; } pk;
  pk.h[0] = __float2bfloat16(a); pk.h[1] = __float2bfloat16(b);
  pk.h[2] = __float2bfloat16(c); pk.h[3] = __float2bfloat16(d);
  *(uint2*)dst = pk.u;
}

__device__ __forceinline__ float bf2f(short s) {
  union { unsigned u; float f; } cv;
  cv.u = ((unsigned)(unsigned short)s) << 16;
  return cv.f;
}

__device__ __forceinline__ float sum8bf(short8 v) {
  float s = 0.f;
#pragma unroll
  for (int i = 0; i < 8; ++i) s += bf2f(v[i]);
  return s;
}

// ---------------------------------------------------------------- pass 1
// per-(nh,seg): partial S^T = V^T K (64x64) and ksum (64), written to ws.
// Barrier-free main loop: wave w scans positions [w*Lseg/4, (w+1)*Lseg/4)
// in 32-position chunks, private LDS tiles, 16 accumulators = full S^T.
__global__ __launch_bounds__(256, 4) void la_pass1(
    const float* __restrict__ Kg, const float* __restrict__ Vg,
    float* __restrict__ ws, int G, int Lseg) {
  const int bid = blockIdx.x;
  const int nh = bid / G, g = bid % G;
  const int n = nh / Hh, h = nh % Hh;
  const int t = threadIdx.x;
  const int wave = t >> 6, lane = t & 63, m = lane & 15, quad = lane >> 4;
  const int pg = lane & 7, cg = lane >> 3;   // position-group / col-group
  const int j0 = pg * 4, c0 = cg * 8;        // 4 positions x 8 cols per thread

  __shared__ __align__(16) short smem[18432];  // 36.9 KB total
  short* Kt = smem + wave * 2304;              // K^T [e][j], [64][36]
  short* Vt = smem + 9216 + wave * 2304;       // V^T [d][j], [64][36]

  floatx4 acc[4][4];  // S^T tile (db,eb): row d=16db+quad*4+r, col e=16eb+m
  const floatx4 z4 = {0.f, 0.f, 0.f, 0.f};
#pragma unroll
  for (int a = 0; a < 4; ++a)
#pragma unroll
    for (int b = 0; b < 4; ++b) acc[a][b] = z4;
  float kpriv[8] = {0.f, 0.f, 0.f, 0.f, 0.f, 0.f, 0.f, 0.f};

  const int nwc = Lseg >> 7;                      // 32-pos chunks per wave
  const int base_pos = g * Lseg + wave * (Lseg >> 2);

  for (int ch = 0; ch < nwc; ++ch) {
    const int pos = base_pos + ch * 32 + j0;
    const size_t gb = ((size_t)((n * Ll + pos) * Hh + h)) * 64 + c0;
    // ---- K: 8 float4 loads (4 positions x cols c0..c0+7)
    float4 ka0 = *(const float4*)(Kg + gb);
    float4 ka1 = *(const float4*)(Kg + gb + 1024);
    float4 ka2 = *(const float4*)(Kg + gb + 2048);
    float4 ka3 = *(const float4*)(Kg + gb + 3072);
    float4 kb0 = *(const float4*)(Kg + gb + 4);
    float4 kb1 = *(const float4*)(Kg + gb + 1028);
    float4 kb2 = *(const float4*)(Kg + gb + 2052);
    float4 kb3 = *(const float4*)(Kg + gb + 3076);
    ka0 = elu4(ka0); ka1 = elu4(ka1); ka2 = elu4(ka2); ka3 = elu4(ka3);
    kb0 = elu4(kb0); kb1 = elu4(kb1); kb2 = elu4(kb2); kb3 = elu4(kb3);
    kpriv[0] += ka0.x + ka1.x + ka2.x + ka3.x;
    kpriv[1] += ka0.y + ka1.y + ka2.y + ka3.y;
    kpriv[2] += ka0.z + ka1.z + ka2.z + ka3.z;
    kpriv[3] += ka0.w + ka1.w + ka2.w + ka3.w;
    kpriv[4] += kb0.x + kb1.x + kb2.x + kb3.x;
    kpriv[5] += kb0.y + kb1.y + kb2.y + kb3.y;
    kpriv[6] += kb0.z + kb1.z + kb2.z + kb3.z;
    kpriv[7] += kb0.w + kb1.w + kb2.w + kb3.w;
    __hip_bfloat16* ktb = (__hip_bfloat16*)Kt;
    st4bf(&ktb[(c0 + 0) * 36 + j0], ka0.x, ka1.x, ka2.x, ka3.x);
    st4bf(&ktb[(c0 + 1) * 36 + j0], ka0.y, ka1.y, ka2.y, ka3.y);
    st4bf(&ktb[(c0 + 2) * 36 + j0], ka0.z, ka1.z, ka2.z, ka3.z);
    st4bf(&ktb[(c0 + 3) * 36 + j0], ka0.w, ka1.w, ka2.w, ka3.w);
    st4bf(&ktb[(c0 + 4) * 36 + j0], kb0.x, kb1.x, kb2.x, kb3.x);
    st4bf(&ktb[(c0 + 5) * 36 + j0], kb0.y, kb1.y, kb2.y, kb3.y);
    st4bf(&ktb[(c0 + 6) * 36 + j0], kb0.z, kb1.z, kb2.z, kb3.z);
    st4bf(&ktb[(c0 + 7) * 36 + j0], kb0.w, kb1.w, kb2.w, kb3.w);
    // ---- V: 8 float4 loads (no elu)
    float4 va0 = *(const float4*)(Vg + gb);
    float4 va1 = *(const float4*)(Vg + gb + 1024);
    float4 va2 = *(const float4*)(Vg + gb + 2048);
    float4 va3 = *(const float4*)(Vg + gb + 3072);
    float4 vb0 = *(const float4*)(Vg + gb + 4);
    float4 vb1 = *(const float4*)(Vg + gb + 1028);
    float4 vb2 = *(const float4*)(Vg + gb + 2052);
    float4 vb3 = *(const float4*)(Vg + gb + 3076);
    __hip_bfloat16* vtb = (__hip_bfloat16*)Vt;
    st4bf(&vtb[(c0 + 0) * 36 + j0], va0.x, va1.x, va2.x, va3.x);
    st4bf(&vtb[(c0 + 1) * 36 + j0], va0.y, va1.y, va2.y, va3.y);
    st4bf(&vtb[(c0 + 2) * 36 + j0], va0.z, va1.z, va2.z, va3.z);
    st4bf(&vtb[(c0 + 3) * 36 + j0], va0.w, va1.w, va2.w, va3.w);
    st4bf(&vtb[(c0 + 4) * 36 + j0], vb0.x, vb1.x, vb2.x, vb3.x);
    st4bf(&vtb[(c0 + 5) * 36 + j0], vb0.y, vb1.y, vb2.y, vb3.y);
    st4bf(&vtb[(c0 + 6) * 36 + j0], vb0.z, vb1.z, vb2.z, vb3.z);
    st4bf(&vtb[(c0 + 7) * 36 + j0], vb0.w, vb1.w, vb2.w, vb3.w);
    // ---- fragments + 16 MFMAs (wave-local lgkm dependency, no barrier)
    short8 af[4], bf[4];
#pragma unroll
    for (int db = 0; db < 4; ++db) af[db] = frag36(Vt, 16 * db + m, quad);
#pragma unroll
    for (int eb = 0; eb < 4; ++eb) bf[eb] = frag36(Kt, 16 * eb + m, quad);
    __builtin_amdgcn_s_setprio(1);
#pragma unroll
    for (int db = 0; db < 4; ++db)
#pragma unroll
      for (int eb = 0; eb < 4; ++eb)
        acc[db][eb] = mfma16(af[db], bf[eb], acc[db][eb]);
    __builtin_amdgcn_s_setprio(0);
  }

  // ---- cross-wave reduction: 4 rounds over d-blocks (LDS overlay, f32)
  __syncthreads();  // all waves done with their tiles
  float* redf = (float*)smem;  // [4 waves][16 rows][64 cols] = 16 KB
  const size_t slot = (size_t)bid * SLOT;
#pragma unroll
  for (int db = 0; db < 4; ++db) {
#pragma unroll
    for (int eb = 0; eb < 4; ++eb)
#pragma unroll
      for (int r = 0; r < 4; ++r)
        redf[wave * 1024 + (quad * 4 + r) * 64 + 16 * eb + m] = acc[db][eb][r];
    __syncthreads();
#pragma unroll
    for (int u = 0; u < 4; ++u) {
      const int i = t + 256 * u;
      const float s = redf[i] + redf[1024 + i] + redf[2048 + i] + redf[3072 + i];
      ws[slot + (16 * db + (i >> 6)) * 64 + (i & 63)] = s;
    }
    __syncthreads();
  }
  // ---- ksum: reduce kpriv over position-lanes, then across waves
#pragma unroll
  for (int u = 0; u < 8; ++u) {
    kpriv[u] += __shfl_xor(kpriv[u], 1);
    kpriv[u] += __shfl_xor(kpriv[u], 2);
    kpriv[u] += __shfl_xor(kpriv[u], 4);
  }
  if (pg == 0)
#pragma unroll
    for (int u = 0; u < 8; ++u) redf[wave * 64 + c0 + u] = kpriv[u];
  __syncthreads();
  if (t < 64)
    ws[slot + 4096 + t] = redf[t] + redf[64 + t] + redf[128 + t] + redf[192 + t];
}

// ---------------------------------------------------------------- pass 2
// exclusive scan over segments; one element per thread, NHh*17 blocks.
__global__ __launch_bounds__(256) void la_pass2(float* __restrict__ ws, int G) {
  const int nh = blockIdx.x / 17, part = blockIdx.x % 17;
  const int idx = part * 256 + threadIdx.x;
  if (idx >= SLOT) return;
  float run = 0.f;
  for (int g = 0; g < G; ++g) {
    const size_t base = (size_t)(nh * G + g) * SLOT;
    const float cur = ws[base + idx];
    ws[base + idx] = run;
    run += cur;
  }
}

// ---------------------------------------------------------------- pass 3
__global__ __launch_bounds__(256, 4) void la_pass3(
    const float* __restrict__ Qg, const float* __restrict__ Kg,
    const float* __restrict__ Vg, const float* __restrict__ ws,
    float* __restrict__ out, int G, int Lseg, int has_prefix) {
  const int bid = blockIdx.x;
  const int nh = bid / G, g = bid % G;
  const int n = nh / Hh, h = nh % Hh;
  const int t = threadIdx.x;
  const int wave = t >> 6, lane = t & 63, m = lane & 15, quad = lane >> 4;
  const int row = t >> 2, q4 = t & 3;      // row-major staging coords
  const int jr0 = m * 4;                   // V 4x4-block transposed staging
  const int er0 = wave * 16 + quad * 4;

  __shared__ __hip_bfloat16 QPb[64 * LDB];  // Q [i][e], then masked P [i][j]
  __shared__ __hip_bfloat16 Kb [64 * LDB];  // K [j][e], then S^T snapshot [d][e]
  __shared__ __hip_bfloat16 Ktb[64 * LDB];  // K^T [e][j]
  __shared__ __hip_bfloat16 Vtb[64 * LDB];  // V^T [d][j]
  __shared__ float ksum[64];
  __shared__ float kpart[4][64];

  const size_t slot = (size_t)bid * SLOT;
  floatx4 Sacc[4];  // persistent S^T: rows d = 16*wave+quad*4+r, cols e = 16*b+m
  const floatx4 z4 = {0.f, 0.f, 0.f, 0.f};
#pragma unroll
  for (int b = 0; b < 4; ++b) {
    Sacc[b] = z4;
    if (has_prefix) {
#pragma unroll
      for (int r = 0; r < 4; ++r)
        Sacc[b][r] = ws[slot + (16 * wave + quad * 4 + r) * 64 + 16 * b + m];
    }
  }
  if (t < 64) ksum[t] = has_prefix ? ws[slot + 4096 + t] : 0.f;

  const int nchunk = Lseg / CCH;
  for (int c = 0; c < nchunk; ++c) {
    const int lbase = g * Lseg + c * CCH;
    // ---- phase A: issue Q,K,V loads; stage Q,K (V deferred to phase C)
    const size_t gbr = ((size_t)((n * Ll + lbase + row) * Hh + h)) * 64;
    const size_t gbv = ((size_t)((n * Ll + lbase + jr0) * Hh + h)) * 64 + er0;
    float4 qr[4], kr[4];
#pragma unroll
    for (int u = 0; u < 4; ++u) {
      const int col = u * 16 + q4 * 4;
      qr[u] = *(const float4*)(Qg + gbr + col);
      kr[u] = *(const float4*)(Kg + gbr + col);
    }
    float4 vr0 = *(const float4*)(Vg + gbv);
    float4 vr1 = *(const float4*)(Vg + gbv + 1024);
    float4 vr2 = *(const float4*)(Vg + gbv + 2048);
    float4 vr3 = *(const float4*)(Vg + gbv + 3072);
#pragma unroll
    for (int u = 0; u < 4; ++u) {
      const int col = u * 16 + q4 * 4;
      float4 qv = elu4(qr[u]);
      float4 kv = elu4(kr[u]);
      st4bf(&QPb[row * LDB + col], qv.x, qv.y, qv.z, qv.w);
      st4bf(&Kb [row * LDB + col], kv.x, kv.y, kv.z, kv.w);
      Ktb[(col + 0) * LDB + row] = __float2bfloat16(kv.x);
      Ktb[(col + 1) * LDB + row] = __float2bfloat16(kv.y);
      Ktb[(col + 2) * LDB + row] = __float2bfloat16(kv.z);
      Ktb[(col + 3) * LDB + row] = __float2bfloat16(kv.w);
    }
    bar_lgkm();  // B1: Q,K tiles staged (V loads still in flight)

    // ---- phase B: m1 (sc = Q K^T) + denominator in registers
    const short8 qa0 = frag_ld(QPb, 16 * wave + m, 0, quad);
    const short8 qa1 = frag_ld(QPb, 16 * wave + m, 1, quad);
    floatx4 sc[4];
    __builtin_amdgcn_s_setprio(1);
#pragma unroll
    for (int b = 0; b < 4; ++b) {
      sc[b] = mfma16(qa0, frag_ld(Kb, 16 * b + m, 0, quad), z4);
      sc[b] = mfma16(qa1, frag_ld(Kb, 16 * b + m, 1, quad), sc[b]);
    }
    __builtin_amdgcn_s_setprio(0);
    // dden for row i' = 16*wave + m from register fragments:
    // qa0 covers e = quad*8..+7, qa1 covers e = 32+quad*8..+7
    float dpart = 0.f;
    {
      const float* ks0 = &ksum[quad * 8];        // broadcast reads
      const float* ks1 = &ksum[32 + quad * 8];
#pragma unroll
      for (int u = 0; u < 8; ++u) dpart += bf2f(qa0[u]) * ks0[u];
#pragma unroll
      for (int u = 0; u < 8; ++u) dpart += bf2f(qa1[u]) * ks1[u];
    }
    dpart += __shfl_xor(dpart, 16);
    dpart += __shfl_xor(dpart, 32);  // all lanes: full dden[16*wave + m]
    // rs[r] = sum_j masked sc; z[r] in registers
    float z[4];
#pragma unroll
    for (int r = 0; r < 4; ++r) {
      const int i = 16 * wave + quad * 4 + r;
      float rs = 0.f;
#pragma unroll
      for (int b = 0; b < 4; ++b) {
        const int j = 16 * b + m;
        rs += (j <= i) ? sc[b][r] : 0.f;
      }
      rs += __shfl_xor(rs, 1);
      rs += __shfl_xor(rs, 2);
      rs += __shfl_xor(rs, 4);
      rs += __shfl_xor(rs, 8);
      const float den = __shfl(dpart, quad * 4 + r);  // lane m' = quad*4+r
      z[r] = 1.f / (den + rs + EPSF);
    }
    bar_lgkm();  // B2: Q/Kb reads done; QPb->P, Kb->snapshot next

    // ---- phase C: masked P -> QPb; S^T snapshot -> Kb; stage V -> Vtb
#pragma unroll
    for (int b = 0; b < 4; ++b)
#pragma unroll
      for (int r = 0; r < 4; ++r) {
        const int i = 16 * wave + quad * 4 + r, j = 16 * b + m;
        QPb[i * LDB + j] = __float2bfloat16(j <= i ? sc[b][r] : 0.f);
        Kb[i * LDB + j] = __float2bfloat16(Sacc[b][r]);  // rows d, cols e
      }
    st4bf(&Vtb[(er0 + 0) * LDB + jr0], vr0.x, vr1.x, vr2.x, vr3.x);
    st4bf(&Vtb[(er0 + 1) * LDB + jr0], vr0.y, vr1.y, vr2.y, vr3.y);
    st4bf(&Vtb[(er0 + 2) * LDB + jr0], vr0.z, vr1.z, vr2.z, vr3.z);
    st4bf(&Vtb[(er0 + 3) * LDB + jr0], vr0.w, vr1.w, vr2.w, vr3.w);
    bar_lgkm();  // B3: P + snapshot + V visible

    // ---- phase D: m2 (Q S_prev) + m3 (P V) + m4 (S += V^T K)
    const short8 pa0 = frag_ld(QPb, 16 * wave + m, 0, quad);
    const short8 pa1 = frag_ld(QPb, 16 * wave + m, 1, quad);
    const short8 va0 = frag_ld(Vtb, 16 * wave + m, 0, quad);
    const short8 va1 = frag_ld(Vtb, 16 * wave + m, 1, quad);
    floatx4 O[4];
    __builtin_amdgcn_s_setprio(1);
#pragma unroll
    for (int b = 0; b < 4; ++b) {
      O[b] = mfma16(qa0, frag_ld(Kb, 16 * b + m, 0, quad), z4);
      O[b] = mfma16(qa1, frag_ld(Kb, 16 * b + m, 1, quad), O[b]);
      O[b] = mfma16(pa0, frag_ld(Vtb, 16 * b + m, 0, quad), O[b]);
      O[b] = mfma16(pa1, frag_ld(Vtb, 16 * b + m, 1, quad), O[b]);
      Sacc[b] = mfma16(va0, frag_ld(Ktb, 16 * b + m, 0, quad), Sacc[b]);
      Sacc[b] = mfma16(va1, frag_ld(Ktb, 16 * b + m, 1, quad), Sacc[b]);
    }
    __builtin_amdgcn_s_setprio(0);
    {  // ksum partials for next chunk
      const short8 x0 = *(const short8*)(&Ktb[lane * LDB + wave * 16]);
      const short8 x1 = *(const short8*)(&Ktb[lane * LDB + wave * 16 + 8]);
      kpart[wave][lane] = sum8bf(x0) + sum8bf(x1);
    }
    const size_t ob = ((size_t)((n * Ll + lbase) * Hh + h)) * 64;
#pragma unroll
    for (int r = 0; r < 4; ++r) {
      const int i = 16 * wave + quad * 4 + r;
#pragma unroll
      for (int b = 0; b < 4; ++b)
        out[ob + (size_t)i * (Hh * 64) + 16 * b + m] = O[b][r] * z[r];
    }
    bar_lgkm();  // B4: all LDS reads of this chunk done (stores NOT drained)
    if (t < 64)
      ksum[t] += kpart[0][t] + kpart[1][t] + kpart[2][t] + kpart[3][t];
  }
}

// ---------------------------------------------------------------- launch
extern "C" void kernel_launch(void* const* d_in, const int* in_sizes, int n_in,
                              void* d_out, int out_size, void* d_ws, size_t ws_size,
                              hipStream_t stream) {
  (void)in_sizes; (void)n_in; (void)out_size;
  const float* Qg = (const float*)d_in[0];
  const float* Kg = (const float*)d_in[1];
  const float* Vg = (const float*)d_in[2];
  float* out = (float*)d_out;
  float* ws = (float*)d_ws;

  const size_t per_seg = (size_t)NHh * SLOT * sizeof(float);
  int G = 1;
  if (ws_size >= 16 * per_seg) G = 16;
  else if (ws_size >= 8 * per_seg) G = 8;
  else if (ws_size >= 4 * per_seg) G = 4;
  else if (ws_size >= 2 * per_seg) G = 2;
  const int Lseg = Ll / G;

  if (G > 1) {
    la_pass1<<<NHh * G, 256, 0, stream>>>(Kg, Vg, ws, G, Lseg);
    la_pass2<<<NHh * 17, 256, 0, stream>>>(ws, G);
  }
  la_pass3<<<NHh * G, 256, 0, stream>>>(Qg, Kg, Vg, ws, out, G, Lseg, G > 1 ? 1 : 0);
}